// Round 3
// baseline (1720.789 us; speedup 1.0000x reference)
//
#include <hip/hip_runtime.h>

// QLlamaAttention on MI355X — round 5: integer-dot GEMM (resubmit of round 4;
// previous bench died in container acquire, no kernel verdict — source
// re-audited: bounds, barrier uniformity, global_load_lds dest uniformity all
// check out).
// Key insight: quant group size (32) == K of mfma_f32_16x16x32_bf16, and the
// quantized integers (|q| <= 128) are EXACT in bf16. One MFMA on raw integers
// gives the exact per-group dot in fp32 (products <= 2^14, 32-term sums
// <= 2^19 < 2^24); then acc += dot * (sx*sw) applies scales per group.
// Replaces the 3-MFMA split-bf16 scheme (drops 2/3 of MFMA work) and halves
// quantized-operand bytes (one bf16 plane instead of hi+lo).
// GEMM staging: global_load_lds width-16 with pre-swizzled global source +
// XOR-swizzled LDS reads (guide §5: swizzle both sides or neither).
// attn_k unchanged from round 3 (direct-V). rope unchanged.
//
// Numerics: GEMM per-group dot exact; 2 fp32 roundings per group term.
// Attention contraction stays split-bf16 (rope output is arbitrary fp32).

typedef __attribute__((ext_vector_type(8))) short bfrag;   // 8 bf16 = 4 VGPR
typedef __attribute__((ext_vector_type(4))) float ffrag;   // MFMA C/D

#define MFMA16(a, b, c) __builtin_amdgcn_mfma_f32_16x16x32_bf16(a, b, c, 0, 0, 0)

__device__ __forceinline__ unsigned short f2bf(float f) {
  unsigned int u = __float_as_uint(f);
  u += 0x7fffu + ((u >> 16) & 1u);            // RNE
  return (unsigned short)(u >> 16);
}
__device__ __forceinline__ float bf2f(unsigned short h) {
  return __uint_as_float(((unsigned int)h) << 16);
}

// ------------------------------------------------------- quantize (int-bf16)
// Writes q (integer, exact in bf16) and per-group scale in group-major layout
// sT[g][row] so GEMM's per-K-step scale staging is coalesced.
__global__ __launch_bounds__(256) void quant_int_k(
    const float* __restrict__ src, unsigned short* __restrict__ dq,
    float* __restrict__ sT, int ngroups, int nrows) {
  int g = blockIdx.x * 256 + threadIdx.x;
  if (g >= ngroups) return;
  int gc = g & 127;                            // group index within a row
  int row = g >> 7;
  float maxq = (gc < 64) ? 7.f : ((gc < 96) ? 31.f : 127.f);
  const float4* p = (const float4*)(src + (size_t)g * 32);
  float4 v[8];
  float amax = 0.f;
#pragma unroll
  for (int i = 0; i < 8; ++i) {
    v[i] = p[i];
    amax = fmaxf(amax, fmaxf(fmaxf(fabsf(v[i].x), fabsf(v[i].y)),
                             fmaxf(fabsf(v[i].z), fabsf(v[i].w))));
  }
  float s = amax / maxq;
  if (s == 0.f) s = 1.f;
  float lc = -maxq - 1.f;
  ushort4* qo = (ushort4*)(dq + (size_t)g * 32);
#pragma unroll
  for (int i = 0; i < 8; ++i) {
    float xs[4] = {v[i].x, v[i].y, v[i].z, v[i].w};
    ushort4 hh;
    unsigned short* hp = (unsigned short*)&hh;
#pragma unroll
    for (int j = 0; j < 4; ++j) {
      float q = rintf(xs[j] / s);              // division to match reference
      q = fminf(fmaxf(q, lc), maxq);
      hp[j] = f2bf(q);                         // integer -> exact bf16
    }
    qo[i] = hh;
  }
  sT[(size_t)gc * nrows + row] = s;
}

// ---------------------------------------------------------------- RoPE
__global__ __launch_bounds__(256) void rope_split_k(
    const float* __restrict__ src, unsigned short* __restrict__ hi,
    unsigned short* __restrict__ lo) {
  int idx = blockIdx.x * 256 + threadIdx.x;    // [0, 2048*32*64)
  int dp = idx & 63;
  int h = (idx >> 6) & 31;
  int tok = idx >> 11;
  int si = tok & 1023;
  size_t base = (size_t)tok * 4096 + h * 128 + dp;
  float x1 = src[base];
  float x2 = src[base + 64];
  float inv = powf(10000.f, -(float)dp * (1.f / 64.f));
  float ang = (float)si * inv;
  float sn, cs;
  sincosf(ang, &sn, &cs);
  float o1 = x1 * cs - x2 * sn;
  float o2 = x2 * cs + x1 * sn;
  unsigned short h1 = f2bf(o1), h2 = f2bf(o2);
  hi[base] = h1;
  lo[base] = f2bf(o1 - bf2f(h1));
  hi[base + 64] = h2;
  lo[base + 64] = f2bf(o2 - bf2f(h2));
}

// ------------------------------------------------------- GEMM (integer dot)
// A[M][K], B[N][K] as bf16 integers; AsT[128][M], BsT[128][N] f32 scales.
// 128x128 block, 4 waves (2x2), BK=64 (2 groups per step).
// LDS tiles are [128][64] bf16 with 16B-chunk XOR swizzle chunk' = chunk^(row&7);
// staged by global_load_lds(16B) from a pre-swizzled global source.
__global__ __launch_bounds__(256, 2) void gemm_int_k(
    const unsigned short* __restrict__ Aq, const float* __restrict__ AsT,
    const unsigned short* __restrict__ Bq, const float* __restrict__ BsT,
    float* __restrict__ Cf, unsigned short* __restrict__ Chi,
    unsigned short* __restrict__ Clo, int M, int N, int K, int mode) {
  __shared__ unsigned short sA[128 * 64];      // 16 KB
  __shared__ unsigned short sB[128 * 64];      // 16 KB
  __shared__ float sSA[256], sSB[256];         // 2 groups x 128 rows
  int tid = threadIdx.x;
  int w = tid >> 6, lane = tid & 63, quad = lane >> 4, c = lane & 15;
  int wm = w >> 1, wn = w & 1;
  int bm = blockIdx.y * 128, bn = blockIdx.x * 128;
  int l8 = lane >> 3, l7 = lane & 7;           // staging: lane -> (row, chunk)
  int sp = tid >> 7, sidx = tid & 127;         // scale staging
  ffrag acc[4][4] = {};
  for (int k0 = 0; k0 < K; k0 += 64) {
    __syncthreads();
    int g = k0 >> 5;
    // ---- scales: 2 groups x 128 rows each side (coalesced, group-major) ----
    sSA[tid] = AsT[(size_t)(g + sp) * M + bm + sidx];
    sSB[tid] = BsT[(size_t)(g + sp) * N + bn + sidx];
    // ---- A/B tiles via global_load_lds (16B/lane, 8 rows per issue) ----
    // LDS linear dest; source chunk pre-swizzled: LDS[row][ch] = G[row][ch^(row&7)]
#pragma unroll
    for (int rr = 0; rr < 4; ++rr) {
      int row = rr * 32 + w * 8 + l8;
      const unsigned short* gA = Aq + (size_t)(bm + row) * K + k0 + ((l7 ^ (row & 7)) * 8);
      const unsigned short* gB = Bq + (size_t)(bn + row) * K + k0 + ((l7 ^ (row & 7)) * 8);
      __builtin_amdgcn_global_load_lds(
          (const __attribute__((address_space(1))) unsigned int*)gA,
          (__attribute__((address_space(3))) unsigned int*)&sA[(rr * 32 + w * 8) * 64],
          16, 0, 0);
      __builtin_amdgcn_global_load_lds(
          (const __attribute__((address_space(1))) unsigned int*)gB,
          (__attribute__((address_space(3))) unsigned int*)&sB[(rr * 32 + w * 8) * 64],
          16, 0, 0);
    }
    __syncthreads();
    // ---- 2 groups: exact integer dot via 1 MFMA, then scale-apply ----
#pragma unroll
    for (int gg2 = 0; gg2 < 2; ++gg2) {
      bfrag av[4], bv[4];
#pragma unroll
      for (int i = 0; i < 4; ++i) {
        int ra = wm * 64 + i * 16 + c;
        int rb = wn * 64 + i * 16 + c;
        av[i] = *(const bfrag*)&sA[ra * 64 + (((gg2 * 4 + quad) ^ (ra & 7)) * 8)];
        bv[i] = *(const bfrag*)&sB[rb * 64 + (((gg2 * 4 + quad) ^ (rb & 7)) * 8)];
      }
      ffrag sx[4];
      float sw[4];
#pragma unroll
      for (int i = 0; i < 4; ++i)
        sx[i] = *(const ffrag*)&sSA[gg2 * 128 + wm * 64 + i * 16 + quad * 4];
#pragma unroll
      for (int j = 0; j < 4; ++j)
        sw[j] = sSB[gg2 * 128 + wn * 64 + j * 16 + c];
      ffrag fzero = {};
#pragma unroll
      for (int i = 0; i < 4; ++i)
#pragma unroll
        for (int j = 0; j < 4; ++j) {
          ffrag dot = MFMA16(av[i], bv[j], fzero);
#pragma unroll
          for (int r = 0; r < 4; ++r)
            acc[i][j][r] += dot[r] * (sx[i][r] * sw[j]);
        }
    }
  }
#pragma unroll
  for (int i = 0; i < 4; ++i)
#pragma unroll
    for (int j = 0; j < 4; ++j) {
      int m0 = bm + wm * 64 + i * 16 + quad * 4;
      int n = bn + wn * 64 + j * 16 + c;
#pragma unroll
      for (int r = 0; r < 4; ++r) {
        float val = acc[i][j][r];
        if (mode == 1) {
          int tok = m0 + r;
          int bb = tok >> 10, si = tok & 1023;
          int hh = n >> 7, d = n & 127;
          size_t o = ((size_t)(bb * 32 + hh) * 128 + d) * 1024 + si;
          unsigned short hv = f2bf(val);
          Chi[o] = hv;
          Clo[o] = f2bf(val - bf2f(hv));
        } else {
          Cf[(size_t)(m0 + r) * N + n] = val;
        }
      }
    }
}

// ---------------------------------------------------------------- attention
// (unchanged from round 3: grid (64 bh fast, 16 qb slow), K staged in LDS
// XOR-swizzled, V direct from global in [b,h,d,s] layout.)
__global__ __launch_bounds__(256, 4) void attn_k(
    const unsigned short* __restrict__ Qh, const unsigned short* __restrict__ Ql,
    const unsigned short* __restrict__ Khg, const unsigned short* __restrict__ Klg,
    const unsigned short* __restrict__ Vhg, const unsigned short* __restrict__ Vlg,
    float* __restrict__ O) {
  __shared__ unsigned short sKh[64 * 128], sKl[64 * 128];   // 16 KB each
  int qb = blockIdx.y, bh = blockIdx.x;
  int b = bh >> 5, h = bh & 31;
  int tid = threadIdx.x;
  int lane = tid & 63, w = tid >> 6, quad = lane >> 4, c = lane & 15;
  int q0 = qb * 64 + w * 16;
  bfrag bqh[4], bql[4];
  {
    const unsigned short* qr = Qh + ((size_t)(b * 1024 + q0 + c)) * 4096 + h * 128 + quad * 8;
    const unsigned short* qrl = Ql + ((size_t)(b * 1024 + q0 + c)) * 4096 + h * 128 + quad * 8;
#pragma unroll
    for (int kd = 0; kd < 4; ++kd) {
      bqh[kd] = *(const bfrag*)(qr + kd * 32);
      bql[kd] = *(const bfrag*)(qrl + kd * 32);
    }
  }
  int kr = tid >> 4, kc = tid & 15;            // K staging: 16 rows/round
  ffrag oacc[8] = {};
  float m_q = -INFINITY, l_q = 0.f;
  const float scale = 0.088388347648318447f;   // 1/sqrt(128)
  const unsigned short* Kb = Khg + ((size_t)b * 1024) * 4096 + h * 128;
  const unsigned short* Klb = Klg + ((size_t)b * 1024) * 4096 + h * 128;
  const unsigned short* Vb = Vhg + ((size_t)bh * 128) * 1024;
  const unsigned short* Vlb = Vlg + ((size_t)bh * 128) * 1024;
  int sA_ = ((quad & 1) << 5) + c;             // P-transpose src lanes
  int sB_ = sA_ + 16;
  for (int kt = 0; kt <= qb; ++kt) {
    __syncthreads();
    {  // ---- stage K tile (64 x 128, hi+lo) ----
      uint4 th[4], tl[4];
#pragma unroll
      for (int rr = 0; rr < 4; ++rr) {
        size_t g = (size_t)(kt * 64 + rr * 16 + kr) * 4096 + kc * 8;
        th[rr] = *(const uint4*)(Kb + g);
        tl[rr] = *(const uint4*)(Klb + g);
      }
#pragma unroll
      for (int rr = 0; rr < 4; ++rr) {
        int row = rr * 16 + kr;
        int off = (row * 16 + (kc ^ (row & 15))) * 8;
        *(uint4*)&sKh[off] = th[rr];
        *(uint4*)&sKl[off] = tl[rr];
      }
    }
    __syncthreads();
    // ---- S = K Q^T : D[row=key=quad*4+r, col=q=c] ----
    ffrag sf[4] = {};
#pragma unroll
    for (int kd = 0; kd < 4; ++kd) {
      bfrag ah[4], al[4];
#pragma unroll
      for (int kb = 0; kb < 4; ++kb) {
        int off = ((kb * 16 + c) * 16 + ((kd * 4 + quad) ^ c)) * 8;
        ah[kb] = *(const bfrag*)&sKh[off];
        al[kb] = *(const bfrag*)&sKl[off];
      }
#pragma unroll
      for (int kb = 0; kb < 4; ++kb) {
        sf[kb] = MFMA16(ah[kb], bqh[kd], sf[kb]);
        sf[kb] = MFMA16(ah[kb], bql[kd], sf[kb]);
        sf[kb] = MFMA16(al[kb], bqh[kd], sf[kb]);
      }
    }
    // ---- scale + causal mask + row max (per q = lane&15) ----
    float rmax = -INFINITY;
    bool diag = (kt == qb);
#pragma unroll
    for (int kb = 0; kb < 4; ++kb)
#pragma unroll
      for (int r = 0; r < 4; ++r) {
        float v = sf[kb][r] * scale;
        if (diag && (kb * 16 + quad * 4 + r) > (w * 16 + c)) v = -1e30f;
        sf[kb][r] = v;
        rmax = fmaxf(rmax, v);
      }
    rmax = fmaxf(rmax, __shfl_xor(rmax, 16, 64));
    rmax = fmaxf(rmax, __shfl_xor(rmax, 32, 64));
    float mn = fmaxf(m_q, rmax);
    float alpha = __expf(m_q - mn);
    m_q = mn;
    // ---- transpose S to A-layout (shuffles), exp, split hi/lo ----
    bfrag ph[2], pl[2];
    float rsum = 0.f;
#pragma unroll
    for (int sblk = 0; sblk < 2; ++sblk)
#pragma unroll
      for (int j = 0; j < 8; ++j) {
        int srclane = (j < 4) ? sA_ : sB_;
        float v0 = __shfl(sf[sblk * 2 + 0][j & 3], srclane, 64);
        float v1 = __shfl(sf[sblk * 2 + 1][j & 3], srclane, 64);
        float v = (quad < 2) ? v0 : v1;
        float p = __expf(v - m_q);
        rsum += p;
        unsigned short hp = f2bf(p);
        ph[sblk][j] = (short)hp;
        pl[sblk][j] = (short)f2bf(p - bf2f(hp));
      }
    rsum += __shfl_xor(rsum, 16, 64);
    rsum += __shfl_xor(rsum, 32, 64);
    l_q = l_q * alpha + rsum;
    float al4[4];
#pragma unroll
    for (int r = 0; r < 4; ++r) al4[r] = __shfl(alpha, quad * 4 + r, 64);
#pragma unroll
    for (int db = 0; db < 8; ++db)
#pragma unroll
      for (int r = 0; r < 4; ++r) oacc[db][r] *= al4[r];
    // ---- O += P Vt : D[row=q=quad*4+r, col=d=c] ----
#pragma unroll
    for (int db = 0; db < 8; ++db) {
      const unsigned short* vrow = Vb + (size_t)(db * 16 + c) * 1024 + kt * 64;
      const unsigned short* vrowl = Vlb + (size_t)(db * 16 + c) * 1024 + kt * 64;
#pragma unroll
      for (int sblk = 0; sblk < 2; ++sblk) {
        bfrag vh_ = *(const bfrag*)(vrow + (sblk * 4 + quad) * 8);
        bfrag vl_ = *(const bfrag*)(vrowl + (sblk * 4 + quad) * 8);
        oacc[db] = MFMA16(ph[sblk], vh_, oacc[db]);
        oacc[db] = MFMA16(ph[sblk], vl_, oacc[db]);
        oacc[db] = MFMA16(pl[sblk], vh_, oacc[db]);
      }
    }
  }
  float invl[4];
#pragma unroll
  for (int r = 0; r < 4; ++r) invl[r] = 1.f / __shfl(l_q, quad * 4 + r, 64);
#pragma unroll
  for (int db = 0; db < 8; ++db)
#pragma unroll
    for (int r = 0; r < 4; ++r)
      O[((size_t)(b * 1024 + q0 + quad * 4 + r)) * 4096 + h * 128 + db * 16 + c] =
          oacc[db][r] * invl[r];
}

// ---------------------------------------------------------------- launcher
extern "C" void kernel_launch(void* const* d_in, const int* in_sizes, int n_in,
                              void* d_out, int out_size, void* d_ws, size_t ws_size,
                              hipStream_t stream) {
  (void)in_sizes; (void)n_in; (void)out_size; (void)ws_size;
  const float* x = (const float*)d_in[0];
  const float* Wq = (const float*)d_in[1];
  const float* Wk = (const float*)d_in[2];
  const float* Wv = (const float*)d_in[3];
  const float* Wo = (const float*)d_in[4];
  float* out = (float*)d_out;
  char* ws = (char*)d_ws;
  const size_t MB = 1024ull * 1024ull;
  unsigned short* Xq = (unsigned short*)(ws);              // 16 MB (bf16 ints)
  float* Xs = (float*)(ws + 16 * MB);                      // 1 MB  (128 x 2048)
  unsigned short* Wqq = (unsigned short*)(ws + 24 * MB);   // 32 MB (bf16 ints)
  float* Ws = (float*)(ws + 56 * MB);                      // 2 MB  (128 x 4096)
  float* S1 = (float*)(ws + 64 * MB);                      // 32 MB fp32
  unsigned short* Qh = (unsigned short*)(ws + 96 * MB);    // 16 MB
  unsigned short* Ql = (unsigned short*)(ws + 112 * MB);
  unsigned short* Kh = (unsigned short*)(ws + 128 * MB);
  unsigned short* Kl = (unsigned short*)(ws + 144 * MB);
  unsigned short* Vh = (unsigned short*)(ws + 160 * MB);   // transposed [b,h,d,s]
  unsigned short* Vl = (unsigned short*)(ws + 176 * MB);

  dim3 gg(32, 16), gb(256);
  quant_int_k<<<1024, 256, 0, stream>>>(x, Xq, Xs, 2048 * 128, 2048);
  quant_int_k<<<2048, 256, 0, stream>>>(Wq, Wqq, Ws, 4096 * 128, 4096);
  gemm_int_k<<<gg, gb, 0, stream>>>(Xq, Xs, Wqq, Ws, S1, nullptr, nullptr,
                                    2048, 4096, 4096, 0);
  rope_split_k<<<16384, 256, 0, stream>>>(S1, Qh, Ql);
  quant_int_k<<<2048, 256, 0, stream>>>(Wk, Wqq, Ws, 4096 * 128, 4096);
  gemm_int_k<<<gg, gb, 0, stream>>>(Xq, Xs, Wqq, Ws, S1, nullptr, nullptr,
                                    2048, 4096, 4096, 0);
  rope_split_k<<<16384, 256, 0, stream>>>(S1, Kh, Kl);
  quant_int_k<<<2048, 256, 0, stream>>>(Wv, Wqq, Ws, 4096 * 128, 4096);
  gemm_int_k<<<gg, gb, 0, stream>>>(Xq, Xs, Wqq, Ws, nullptr, Vh, Vl,
                                    2048, 4096, 4096, 1);
  attn_k<<<dim3(64, 16), 256, 0, stream>>>(Qh, Ql, Kh, Kl, Vh, Vl, S1);
  quant_int_k<<<1024, 256, 0, stream>>>(S1, Xq, Xs, 2048 * 128, 2048);
  quant_int_k<<<2048, 256, 0, stream>>>(Wo, Wqq, Ws, 4096 * 128, 4096);
  gemm_int_k<<<gg, gb, 0, stream>>>(Xq, Xs, Wqq, Ws, out, nullptr, nullptr,
                                    2048, 4096, 4096, 0);
}

// Round 4
// 1103.812 us; speedup vs baseline: 1.5590x; 1.5590x over previous
//
#include <hip/hip_runtime.h>

// QLlamaAttention on MI355X — round 6: 2-phase pipelining (T3-minimum).
// Round-3 post-mortem: gemm_int_k was 4x latency-stalled (5800 cyc/K-step vs
// ~1350 issue work; VALUBusy 25%, MfmaUtil 9%, occupancy grid-capped at
// 2 blocks/CU). Fix: double-buffered LDS, ONE barrier per K-step,
// stage(next) issued async via global_load_lds BEFORE compute(cur) so HBM
// latency hides under compute. Scales also staged via global_load_lds
// (width 4) — a load+ds_write pair would stall in-stage on vmcnt.
// attn_k gets the same structure: K staging switched to global_load_lds
// (linear dest + pre-swizzled per-lane source, same LDS content as before),
// double-buffered, stage(kt+1) issued before compute(kt).
// Integer-dot GEMM numerics unchanged (absmax 0.0244).

typedef __attribute__((ext_vector_type(8))) short bfrag;   // 8 bf16 = 4 VGPR
typedef __attribute__((ext_vector_type(4))) float ffrag;   // MFMA C/D

#define MFMA16(a, b, c) __builtin_amdgcn_mfma_f32_16x16x32_bf16(a, b, c, 0, 0, 0)

typedef const __attribute__((address_space(1))) unsigned int* gp_t;
typedef __attribute__((address_space(3))) unsigned int* lp_t;

__device__ __forceinline__ unsigned short f2bf(float f) {
  unsigned int u = __float_as_uint(f);
  u += 0x7fffu + ((u >> 16) & 1u);            // RNE
  return (unsigned short)(u >> 16);
}
__device__ __forceinline__ float bf2f(unsigned short h) {
  return __uint_as_float(((unsigned int)h) << 16);
}

// ------------------------------------------------------- quantize (int-bf16)
__global__ __launch_bounds__(256) void quant_int_k(
    const float* __restrict__ src, unsigned short* __restrict__ dq,
    float* __restrict__ sT, int ngroups, int nrows) {
  int g = blockIdx.x * 256 + threadIdx.x;
  if (g >= ngroups) return;
  int gc = g & 127;                            // group index within a row
  int row = g >> 7;
  float maxq = (gc < 64) ? 7.f : ((gc < 96) ? 31.f : 127.f);
  const float4* p = (const float4*)(src + (size_t)g * 32);
  float4 v[8];
  float amax = 0.f;
#pragma unroll
  for (int i = 0; i < 8; ++i) {
    v[i] = p[i];
    amax = fmaxf(amax, fmaxf(fmaxf(fabsf(v[i].x), fabsf(v[i].y)),
                             fmaxf(fabsf(v[i].z), fabsf(v[i].w))));
  }
  float s = amax / maxq;
  if (s == 0.f) s = 1.f;
  float lc = -maxq - 1.f;
  ushort4* qo = (ushort4*)(dq + (size_t)g * 32);
#pragma unroll
  for (int i = 0; i < 8; ++i) {
    float xs[4] = {v[i].x, v[i].y, v[i].z, v[i].w};
    ushort4 hh;
    unsigned short* hp = (unsigned short*)&hh;
#pragma unroll
    for (int j = 0; j < 4; ++j) {
      float q = rintf(xs[j] / s);              // division to match reference
      q = fminf(fmaxf(q, lc), maxq);
      hp[j] = f2bf(q);                         // integer -> exact bf16
    }
    qo[i] = hh;
  }
  sT[(size_t)gc * nrows + row] = s;
}

// ---------------------------------------------------------------- RoPE
__global__ __launch_bounds__(256) void rope_split_k(
    const float* __restrict__ src, unsigned short* __restrict__ hi,
    unsigned short* __restrict__ lo) {
  int idx = blockIdx.x * 256 + threadIdx.x;    // [0, 2048*32*64)
  int dp = idx & 63;
  int h = (idx >> 6) & 31;
  int tok = idx >> 11;
  int si = tok & 1023;
  size_t base = (size_t)tok * 4096 + h * 128 + dp;
  float x1 = src[base];
  float x2 = src[base + 64];
  float inv = powf(10000.f, -(float)dp * (1.f / 64.f));
  float ang = (float)si * inv;
  float sn, cs;
  sincosf(ang, &sn, &cs);
  float o1 = x1 * cs - x2 * sn;
  float o2 = x2 * cs + x1 * sn;
  unsigned short h1 = f2bf(o1), h2 = f2bf(o2);
  hi[base] = h1;
  lo[base] = f2bf(o1 - bf2f(h1));
  hi[base + 64] = h2;
  lo[base + 64] = f2bf(o2 - bf2f(h2));
}

// ------------------------------------------------------- GEMM (integer dot)
// A[M][K], B[N][K] bf16 integers; AsT[128][M], BsT[128][N] f32 scales.
// 128x128 block, 4 waves (2x2), BK=64 (2 groups/step), double-buffered LDS,
// 2-phase: {barrier; STAGE(next, async); compute(cur)} — 1 barrier/K-step.
__global__ __launch_bounds__(256, 2) void gemm_int_k(
    const unsigned short* __restrict__ Aq, const float* __restrict__ AsT,
    const unsigned short* __restrict__ Bq, const float* __restrict__ BsT,
    float* __restrict__ Cf, unsigned short* __restrict__ Chi,
    unsigned short* __restrict__ Clo, int M, int N, int K, int mode) {
  __shared__ unsigned short sA[2][128 * 64];   // 2 x 16 KB
  __shared__ unsigned short sB[2][128 * 64];   // 2 x 16 KB
  __shared__ float sSA[2][256], sSB[2][256];   // 2 x 2 KB
  int tid = threadIdx.x;
  int w = tid >> 6, lane = tid & 63, quad = lane >> 4, c = lane & 15;
  int wm = w >> 1, wn = w & 1;
  int bm = blockIdx.y * 128, bn = blockIdx.x * 128;
  int l8 = lane >> 3, l7 = lane & 7;           // staging: lane -> (row, chunk)
  int sp = tid >> 7, sidx = tid & 127;         // scale staging index
  ffrag acc[4][4] = {};
  const ffrag fz = {};                         // shared zero C operand

  auto STAGE = [&](int buf, int k0) {
    int g = k0 >> 5;
    // scales: async 4B/lane, wave-uniform dest + per-lane source
    __builtin_amdgcn_global_load_lds(
        (gp_t)(AsT + (size_t)(g + sp) * M + bm + sidx),
        (lp_t)&sSA[buf][w * 64], 4, 0, 0);
    __builtin_amdgcn_global_load_lds(
        (gp_t)(BsT + (size_t)(g + sp) * N + bn + sidx),
        (lp_t)&sSB[buf][w * 64], 4, 0, 0);
    // tiles: 16B/lane, linear dest; source chunk pre-swizzled so that
    // LDS[row][ch] = G[row][ch ^ (row&7)]
#pragma unroll
    for (int rr = 0; rr < 4; ++rr) {
      int row = rr * 32 + w * 8 + l8;
      const unsigned short* gA =
          Aq + (size_t)(bm + row) * K + k0 + ((l7 ^ (row & 7)) * 8);
      const unsigned short* gB =
          Bq + (size_t)(bn + row) * K + k0 + ((l7 ^ (row & 7)) * 8);
      __builtin_amdgcn_global_load_lds((gp_t)gA,
                                       (lp_t)&sA[buf][(rr * 32 + w * 8) * 64],
                                       16, 0, 0);
      __builtin_amdgcn_global_load_lds((gp_t)gB,
                                       (lp_t)&sB[buf][(rr * 32 + w * 8) * 64],
                                       16, 0, 0);
    }
  };

  STAGE(0, 0);
  int nt = K >> 6;
  for (int t = 0; t < nt; ++t) {
    int cur = t & 1;
    __syncthreads();                 // buf[cur] ready (staged last iter);
                                     // everyone done reading buf[cur^1]
    if (t + 1 < nt) STAGE(cur ^ 1, (t + 1) << 6);
#pragma unroll
    for (int gg2 = 0; gg2 < 2; ++gg2) {
      bfrag av[4], bv[4];
#pragma unroll
      for (int i = 0; i < 4; ++i) {
        int ra = wm * 64 + i * 16 + c;
        int rb = wn * 64 + i * 16 + c;
        av[i] = *(const bfrag*)&sA[cur][ra * 64 + (((gg2 * 4 + quad) ^ (ra & 7)) * 8)];
        bv[i] = *(const bfrag*)&sB[cur][rb * 64 + (((gg2 * 4 + quad) ^ (rb & 7)) * 8)];
      }
      ffrag sx[4];
      float sw4[4];
#pragma unroll
      for (int i = 0; i < 4; ++i)
        sx[i] = *(const ffrag*)&sSA[cur][gg2 * 128 + wm * 64 + i * 16 + quad * 4];
#pragma unroll
      for (int j = 0; j < 4; ++j)
        sw4[j] = sSB[cur][gg2 * 128 + wn * 64 + j * 16 + c];
#pragma unroll
      for (int i = 0; i < 4; ++i)
#pragma unroll
        for (int j = 0; j < 4; ++j) {
          ffrag dot = MFMA16(av[i], bv[j], fz);
          acc[i][j] += dot * (sx[i] * sw4[j]);   // vector form -> v_pk_fma
        }
    }
  }
#pragma unroll
  for (int i = 0; i < 4; ++i)
#pragma unroll
    for (int j = 0; j < 4; ++j) {
      int m0 = bm + wm * 64 + i * 16 + quad * 4;
      int n = bn + wn * 64 + j * 16 + c;
#pragma unroll
      for (int r = 0; r < 4; ++r) {
        float val = acc[i][j][r];
        if (mode == 1) {
          int tok = m0 + r;
          int bb = tok >> 10, si = tok & 1023;
          int hh = n >> 7, d = n & 127;
          size_t o = ((size_t)(bb * 32 + hh) * 128 + d) * 1024 + si;
          unsigned short hv = f2bf(val);
          Chi[o] = hv;
          Clo[o] = f2bf(val - bf2f(hv));
        } else {
          Cf[(size_t)(m0 + r) * N + n] = val;
        }
      }
    }
}

// ---------------------------------------------------------------- attention
// Round 6: double-buffered K tiles staged via global_load_lds (linear dest,
// pre-swizzled per-lane source: LDS[row][ch] = G[row][ch^(row&15)], identical
// content to the old reg-staged XOR writes). One barrier per kt; stage(kt+1)
// issued async before compute(kt). V direct from global (L2-resident).
__global__ __launch_bounds__(256, 2) void attn_k(
    const unsigned short* __restrict__ Qh, const unsigned short* __restrict__ Ql,
    const unsigned short* __restrict__ Khg, const unsigned short* __restrict__ Klg,
    const unsigned short* __restrict__ Vhg, const unsigned short* __restrict__ Vlg,
    float* __restrict__ O) {
  __shared__ unsigned short sKh[2][64 * 128], sKl[2][64 * 128];  // 2 x 32 KB
  int qb = blockIdx.y, bh = blockIdx.x;
  int b = bh >> 5, h = bh & 31;
  int tid = threadIdx.x;
  int lane = tid & 63, w = tid >> 6, quad = lane >> 4, c = lane & 15;
  int q0 = qb * 64 + w * 16;
  bfrag bqh[4], bql[4];
  {
    const unsigned short* qr = Qh + ((size_t)(b * 1024 + q0 + c)) * 4096 + h * 128 + quad * 8;
    const unsigned short* qrl = Ql + ((size_t)(b * 1024 + q0 + c)) * 4096 + h * 128 + quad * 8;
#pragma unroll
    for (int kd = 0; kd < 4; ++kd) {
      bqh[kd] = *(const bfrag*)(qr + kd * 32);
      bql[kd] = *(const bfrag*)(qrl + kd * 32);
    }
  }
  ffrag oacc[8] = {};
  float m_q = -INFINITY, l_q = 0.f;
  const float scale = 0.088388347648318447f;   // 1/sqrt(128)
  const unsigned short* Kb = Khg + ((size_t)b * 1024) * 4096 + h * 128;
  const unsigned short* Klb = Klg + ((size_t)b * 1024) * 4096 + h * 128;
  const unsigned short* Vb = Vhg + ((size_t)bh * 128) * 1024;
  const unsigned short* Vlb = Vlg + ((size_t)bh * 128) * 1024;
  int sA_ = ((quad & 1) << 5) + c;             // P-transpose src lanes
  int sB_ = sA_ + 16;
  int sr = lane >> 4, sch = lane & 15;         // staging: lane -> (subrow, chunk)

  auto STAGEK = [&](int buf, int kt) {
    // per issue: 64 lanes x 16B = 4 rows of 128 shorts; wave w, issue rr
    // covers rows rr*16 + w*4 .. +3.
#pragma unroll
    for (int rr = 0; rr < 4; ++rr) {
      int row = rr * 16 + w * 4 + sr;
      size_t g = (size_t)(kt * 64 + row) * 4096 + ((sch ^ (row & 15)) * 8);
      __builtin_amdgcn_global_load_lds((gp_t)(Kb + g),
                                       (lp_t)&sKh[buf][(rr * 16 + w * 4) * 128],
                                       16, 0, 0);
      __builtin_amdgcn_global_load_lds((gp_t)(Klb + g),
                                       (lp_t)&sKl[buf][(rr * 16 + w * 4) * 128],
                                       16, 0, 0);
    }
  };

  STAGEK(0, 0);
  for (int kt = 0; kt <= qb; ++kt) {
    int cur = kt & 1;
    __syncthreads();                 // buf[cur] staged; prev reads of
                                     // buf[cur^1] complete
    if (kt < qb) STAGEK(cur ^ 1, kt + 1);
    // ---- S = K Q^T : D[row=key=quad*4+r, col=q=c] ----
    ffrag sf[4] = {};
#pragma unroll
    for (int kd = 0; kd < 4; ++kd) {
      bfrag ah[4], al[4];
#pragma unroll
      for (int kb = 0; kb < 4; ++kb) {
        int off = ((kb * 16 + c) * 16 + ((kd * 4 + quad) ^ c)) * 8;
        ah[kb] = *(const bfrag*)&sKh[cur][off];
        al[kb] = *(const bfrag*)&sKl[cur][off];
      }
#pragma unroll
      for (int kb = 0; kb < 4; ++kb) {
        sf[kb] = MFMA16(ah[kb], bqh[kd], sf[kb]);
        sf[kb] = MFMA16(ah[kb], bql[kd], sf[kb]);
        sf[kb] = MFMA16(al[kb], bqh[kd], sf[kb]);
      }
    }
    // ---- scale + causal mask + row max (per q = lane&15) ----
    float rmax = -INFINITY;
    bool diag = (kt == qb);
#pragma unroll
    for (int kb = 0; kb < 4; ++kb)
#pragma unroll
      for (int r = 0; r < 4; ++r) {
        float v = sf[kb][r] * scale;
        if (diag && (kb * 16 + quad * 4 + r) > (w * 16 + c)) v = -1e30f;
        sf[kb][r] = v;
        rmax = fmaxf(rmax, v);
      }
    rmax = fmaxf(rmax, __shfl_xor(rmax, 16, 64));
    rmax = fmaxf(rmax, __shfl_xor(rmax, 32, 64));
    float mn = fmaxf(m_q, rmax);
    float alpha = __expf(m_q - mn);
    m_q = mn;
    // ---- transpose S to A-layout (shuffles), exp, split hi/lo ----
    bfrag ph[2], pl[2];
    float rsum = 0.f;
#pragma unroll
    for (int sblk = 0; sblk < 2; ++sblk)
#pragma unroll
      for (int j = 0; j < 8; ++j) {
        int srclane = (j < 4) ? sA_ : sB_;
        float v0 = __shfl(sf[sblk * 2 + 0][j & 3], srclane, 64);
        float v1 = __shfl(sf[sblk * 2 + 1][j & 3], srclane, 64);
        float v = (quad < 2) ? v0 : v1;
        float p = __expf(v - m_q);
        rsum += p;
        unsigned short hp = f2bf(p);
        ph[sblk][j] = (short)hp;
        pl[sblk][j] = (short)f2bf(p - bf2f(hp));
      }
    rsum += __shfl_xor(rsum, 16, 64);
    rsum += __shfl_xor(rsum, 32, 64);
    l_q = l_q * alpha + rsum;
    float al4[4];
#pragma unroll
    for (int r = 0; r < 4; ++r) al4[r] = __shfl(alpha, quad * 4 + r, 64);
#pragma unroll
    for (int db = 0; db < 8; ++db)
#pragma unroll
      for (int r = 0; r < 4; ++r) oacc[db][r] *= al4[r];
    // ---- O += P Vt : D[row=q=quad*4+r, col=d=c] ----
#pragma unroll
    for (int db = 0; db < 8; ++db) {
      const unsigned short* vrow = Vb + (size_t)(db * 16 + c) * 1024 + kt * 64;
      const unsigned short* vrowl = Vlb + (size_t)(db * 16 + c) * 1024 + kt * 64;
#pragma unroll
      for (int sblk = 0; sblk < 2; ++sblk) {
        bfrag vh_ = *(const bfrag*)(vrow + (sblk * 4 + quad) * 8);
        bfrag vl_ = *(const bfrag*)(vrowl + (sblk * 4 + quad) * 8);
        oacc[db] = MFMA16(ph[sblk], vh_, oacc[db]);
        oacc[db] = MFMA16(ph[sblk], vl_, oacc[db]);
        oacc[db] = MFMA16(pl[sblk], vh_, oacc[db]);
      }
    }
  }
  float invl[4];
#pragma unroll
  for (int r = 0; r < 4; ++r) invl[r] = 1.f / __shfl(l_q, quad * 4 + r, 64);
#pragma unroll
  for (int db = 0; db < 8; ++db)
#pragma unroll
    for (int r = 0; r < 4; ++r)
      O[((size_t)(b * 1024 + q0 + quad * 4 + r)) * 4096 + h * 128 + db * 16 + c] =
          oacc[db][r] * invl[r];
}

// ---------------------------------------------------------------- launcher
extern "C" void kernel_launch(void* const* d_in, const int* in_sizes, int n_in,
                              void* d_out, int out_size, void* d_ws, size_t ws_size,
                              hipStream_t stream) {
  (void)in_sizes; (void)n_in; (void)out_size; (void)ws_size;
  const float* x = (const float*)d_in[0];
  const float* Wq = (const float*)d_in[1];
  const float* Wk = (const float*)d_in[2];
  const float* Wv = (const float*)d_in[3];
  const float* Wo = (const float*)d_in[4];
  float* out = (float*)d_out;
  char* ws = (char*)d_ws;
  const size_t MB = 1024ull * 1024ull;
  unsigned short* Xq = (unsigned short*)(ws);              // 16 MB (bf16 ints)
  float* Xs = (float*)(ws + 16 * MB);                      // 1 MB  (128 x 2048)
  unsigned short* Wqq = (unsigned short*)(ws + 24 * MB);   // 32 MB (bf16 ints)
  float* Ws = (float*)(ws + 56 * MB);                      // 2 MB  (128 x 4096)
  float* S1 = (float*)(ws + 64 * MB);                      // 32 MB fp32
  unsigned short* Qh = (unsigned short*)(ws + 96 * MB);    // 16 MB
  unsigned short* Ql = (unsigned short*)(ws + 112 * MB);
  unsigned short* Kh = (unsigned short*)(ws + 128 * MB);
  unsigned short* Kl = (unsigned short*)(ws + 144 * MB);
  unsigned short* Vh = (unsigned short*)(ws + 160 * MB);   // transposed [b,h,d,s]
  unsigned short* Vl = (unsigned short*)(ws + 176 * MB);

  dim3 gg(32, 16), gb(256);
  quant_int_k<<<1024, 256, 0, stream>>>(x, Xq, Xs, 2048 * 128, 2048);
  quant_int_k<<<2048, 256, 0, stream>>>(Wq, Wqq, Ws, 4096 * 128, 4096);
  gemm_int_k<<<gg, gb, 0, stream>>>(Xq, Xs, Wqq, Ws, S1, nullptr, nullptr,
                                    2048, 4096, 4096, 0);
  rope_split_k<<<16384, 256, 0, stream>>>(S1, Qh, Ql);
  quant_int_k<<<2048, 256, 0, stream>>>(Wk, Wqq, Ws, 4096 * 128, 4096);
  gemm_int_k<<<gg, gb, 0, stream>>>(Xq, Xs, Wqq, Ws, S1, nullptr, nullptr,
                                    2048, 4096, 4096, 0);
  rope_split_k<<<16384, 256, 0, stream>>>(S1, Kh, Kl);
  quant_int_k<<<2048, 256, 0, stream>>>(Wv, Wqq, Ws, 4096 * 128, 4096);
  gemm_int_k<<<gg, gb, 0, stream>>>(Xq, Xs, Wqq, Ws, nullptr, Vh, Vl,
                                    2048, 4096, 4096, 1);
  attn_k<<<dim3(64, 16), 256, 0, stream>>>(Qh, Ql, Kh, Kl, Vh, Vl, S1);
  quant_int_k<<<1024, 256, 0, stream>>>(S1, Xq, Xs, 2048 * 128, 2048);
  quant_int_k<<<2048, 256, 0, stream>>>(Wo, Wqq, Ws, 4096 * 128, 4096);
  gemm_int_k<<<gg, gb, 0, stream>>>(Xq, Xs, Wqq, Ws, out, nullptr, nullptr,
                                    2048, 4096, 4096, 0);
}

// Round 5
// 1022.976 us; speedup vs baseline: 1.6821x; 1.0790x over previous
//
#include <hip/hip_runtime.h>

// QLlamaAttention on MI355X — round 7.
//  * gemm_int_k: 512 threads / 8 waves (2x4, each wave 64x32 of the 128^2
//    tile). Same 2-phase double-buffered global_load_lds pipeline. Rationale:
//    round-6 gemm was ~2.5x latency-stalled at 2 waves/SIMD; the MFMA->VALU
//    scale-apply chain needs TLP. 8 waves -> 4 waves/SIMD, acc halves to 32
//    VGPR so the allocator can keep more dot-tiles in flight.
//  * attn_k: + T5 s_setprio around MFMA clusters; + T13 defer-max
//    (RESCALE_THRESHOLD=8): skip O-rescale/alpha shuffles when the new tile
//    max doesn't exceed m+8 (P bounded by e^8, exact normalization at end).
// Integer-dot GEMM numerics unchanged (absmax 0.0244).

typedef __attribute__((ext_vector_type(8))) short bfrag;   // 8 bf16 = 4 VGPR
typedef __attribute__((ext_vector_type(4))) float ffrag;   // MFMA C/D

#define MFMA16(a, b, c) __builtin_amdgcn_mfma_f32_16x16x32_bf16(a, b, c, 0, 0, 0)

typedef const __attribute__((address_space(1))) unsigned int* gp_t;
typedef __attribute__((address_space(3))) unsigned int* lp_t;

__device__ __forceinline__ unsigned short f2bf(float f) {
  unsigned int u = __float_as_uint(f);
  u += 0x7fffu + ((u >> 16) & 1u);            // RNE
  return (unsigned short)(u >> 16);
}
__device__ __forceinline__ float bf2f(unsigned short h) {
  return __uint_as_float(((unsigned int)h) << 16);
}

// ------------------------------------------------------- quantize (int-bf16)
__global__ __launch_bounds__(256) void quant_int_k(
    const float* __restrict__ src, unsigned short* __restrict__ dq,
    float* __restrict__ sT, int ngroups, int nrows) {
  int g = blockIdx.x * 256 + threadIdx.x;
  if (g >= ngroups) return;
  int gc = g & 127;                            // group index within a row
  int row = g >> 7;
  float maxq = (gc < 64) ? 7.f : ((gc < 96) ? 31.f : 127.f);
  const float4* p = (const float4*)(src + (size_t)g * 32);
  float4 v[8];
  float amax = 0.f;
#pragma unroll
  for (int i = 0; i < 8; ++i) {
    v[i] = p[i];
    amax = fmaxf(amax, fmaxf(fmaxf(fabsf(v[i].x), fabsf(v[i].y)),
                             fmaxf(fabsf(v[i].z), fabsf(v[i].w))));
  }
  float s = amax / maxq;
  if (s == 0.f) s = 1.f;
  float lc = -maxq - 1.f;
  ushort4* qo = (ushort4*)(dq + (size_t)g * 32);
#pragma unroll
  for (int i = 0; i < 8; ++i) {
    float xs[4] = {v[i].x, v[i].y, v[i].z, v[i].w};
    ushort4 hh;
    unsigned short* hp = (unsigned short*)&hh;
#pragma unroll
    for (int j = 0; j < 4; ++j) {
      float q = rintf(xs[j] / s);              // division to match reference
      q = fminf(fmaxf(q, lc), maxq);
      hp[j] = f2bf(q);                         // integer -> exact bf16
    }
    qo[i] = hh;
  }
  sT[(size_t)gc * nrows + row] = s;
}

// ---------------------------------------------------------------- RoPE
__global__ __launch_bounds__(256) void rope_split_k(
    const float* __restrict__ src, unsigned short* __restrict__ hi,
    unsigned short* __restrict__ lo) {
  int idx = blockIdx.x * 256 + threadIdx.x;    // [0, 2048*32*64)
  int dp = idx & 63;
  int h = (idx >> 6) & 31;
  int tok = idx >> 11;
  int si = tok & 1023;
  size_t base = (size_t)tok * 4096 + h * 128 + dp;
  float x1 = src[base];
  float x2 = src[base + 64];
  float inv = powf(10000.f, -(float)dp * (1.f / 64.f));
  float ang = (float)si * inv;
  float sn, cs;
  sincosf(ang, &sn, &cs);
  float o1 = x1 * cs - x2 * sn;
  float o2 = x2 * cs + x1 * sn;
  unsigned short h1 = f2bf(o1), h2 = f2bf(o2);
  hi[base] = h1;
  lo[base] = f2bf(o1 - bf2f(h1));
  hi[base + 64] = h2;
  lo[base + 64] = f2bf(o2 - bf2f(h2));
}

// ------------------------------------------------------- GEMM (integer dot)
// A[M][K], B[N][K] bf16 integers; AsT[128][M], BsT[128][N] f32 scales.
// 128x128 block, 8 waves (2x4: wave tile 64x32), BK=64 (2 groups/step),
// double-buffered LDS, 2-phase: {barrier; STAGE(next); compute(cur)}.
__global__ __launch_bounds__(512, 4) void gemm_int_k(
    const unsigned short* __restrict__ Aq, const float* __restrict__ AsT,
    const unsigned short* __restrict__ Bq, const float* __restrict__ BsT,
    float* __restrict__ Cf, unsigned short* __restrict__ Chi,
    unsigned short* __restrict__ Clo, int M, int N, int K, int mode) {
  __shared__ unsigned short sA[2][128 * 64];   // 2 x 16 KB
  __shared__ unsigned short sB[2][128 * 64];   // 2 x 16 KB
  __shared__ float sSA[2][256], sSB[2][256];   // 2 x 2 KB
  int tid = threadIdx.x;
  int w = tid >> 6, lane = tid & 63, quad = lane >> 4, c = lane & 15;
  int wm = w >> 2, wn = w & 3;                 // 2 x 4 waves; tile 64 x 32
  int bm = blockIdx.y * 128, bn = blockIdx.x * 128;
  int l8 = lane >> 3, l7 = lane & 7;           // staging: lane -> (row, chunk)
  ffrag acc[4][2] = {};
  const ffrag fz = {};                         // shared zero C operand

  auto STAGE = [&](int buf, int k0) {
    int g = k0 >> 5;
    // scales: waves 0-3 -> sSA (2 groups x 128 rows), waves 4-7 -> sSB
    {
      int w2 = w & 3;
      const float* sp = (w < 4)
          ? (AsT + (size_t)(g + (w2 >> 1)) * M + bm + (w2 & 1) * 64 + lane)
          : (BsT + (size_t)(g + (w2 >> 1)) * N + bn + (w2 & 1) * 64 + lane);
      lp_t dst = (w < 4) ? (lp_t)&sSA[buf][w2 * 64] : (lp_t)&sSB[buf][w2 * 64];
      __builtin_amdgcn_global_load_lds((gp_t)sp, dst, 4, 0, 0);
    }
    // tiles: 16B/lane, linear dest; source chunk pre-swizzled so that
    // LDS[row][ch] = G[row][ch ^ (row&7)]. Per issue: 8 waves x 1KB = 64 rows.
#pragma unroll
    for (int rr = 0; rr < 2; ++rr) {
      int row = rr * 64 + w * 8 + l8;
      const unsigned short* gA =
          Aq + (size_t)(bm + row) * K + k0 + ((l7 ^ (row & 7)) * 8);
      const unsigned short* gB =
          Bq + (size_t)(bn + row) * K + k0 + ((l7 ^ (row & 7)) * 8);
      __builtin_amdgcn_global_load_lds((gp_t)gA,
                                       (lp_t)&sA[buf][(rr * 64 + w * 8) * 64],
                                       16, 0, 0);
      __builtin_amdgcn_global_load_lds((gp_t)gB,
                                       (lp_t)&sB[buf][(rr * 64 + w * 8) * 64],
                                       16, 0, 0);
    }
  };

  STAGE(0, 0);
  int nt = K >> 6;
  for (int t = 0; t < nt; ++t) {
    int cur = t & 1;
    __syncthreads();                 // buf[cur] ready (staged last iter);
                                     // everyone done reading buf[cur^1]
    if (t + 1 < nt) STAGE(cur ^ 1, (t + 1) << 6);
#pragma unroll
    for (int gg2 = 0; gg2 < 2; ++gg2) {
      bfrag av[4], bv[2];
#pragma unroll
      for (int i = 0; i < 4; ++i) {
        int ra = wm * 64 + i * 16 + c;
        av[i] = *(const bfrag*)&sA[cur][ra * 64 + (((gg2 * 4 + quad) ^ (ra & 7)) * 8)];
      }
#pragma unroll
      for (int j = 0; j < 2; ++j) {
        int rb = wn * 32 + j * 16 + c;
        bv[j] = *(const bfrag*)&sB[cur][rb * 64 + (((gg2 * 4 + quad) ^ (rb & 7)) * 8)];
      }
      ffrag sx[4];
      float sw4[2];
#pragma unroll
      for (int i = 0; i < 4; ++i)
        sx[i] = *(const ffrag*)&sSA[cur][gg2 * 128 + wm * 64 + i * 16 + quad * 4];
#pragma unroll
      for (int j = 0; j < 2; ++j)
        sw4[j] = sSB[cur][gg2 * 128 + wn * 32 + j * 16 + c];
      __builtin_amdgcn_s_setprio(1);
#pragma unroll
      for (int i = 0; i < 4; ++i)
#pragma unroll
        for (int j = 0; j < 2; ++j) {
          ffrag dot = MFMA16(av[i], bv[j], fz);
          acc[i][j] += dot * (sx[i] * sw4[j]);   // vector form -> v_pk_fma
        }
      __builtin_amdgcn_s_setprio(0);
    }
  }
#pragma unroll
  for (int i = 0; i < 4; ++i)
#pragma unroll
    for (int j = 0; j < 2; ++j) {
      int m0 = bm + wm * 64 + i * 16 + quad * 4;
      int n = bn + wn * 32 + j * 16 + c;
#pragma unroll
      for (int r = 0; r < 4; ++r) {
        float val = acc[i][j][r];
        if (mode == 1) {
          int tok = m0 + r;
          int bb = tok >> 10, si = tok & 1023;
          int hh = n >> 7, d = n & 127;
          size_t o = ((size_t)(bb * 32 + hh) * 128 + d) * 1024 + si;
          unsigned short hv = f2bf(val);
          Chi[o] = hv;
          Clo[o] = f2bf(val - bf2f(hv));
        } else {
          Cf[(size_t)(m0 + r) * N + n] = val;
        }
      }
    }
}

// ---------------------------------------------------------------- attention
// Round 7: + setprio around MFMA clusters, + defer-max (THR=8).
__global__ __launch_bounds__(256, 2) void attn_k(
    const unsigned short* __restrict__ Qh, const unsigned short* __restrict__ Ql,
    const unsigned short* __restrict__ Khg, const unsigned short* __restrict__ Klg,
    const unsigned short* __restrict__ Vhg, const unsigned short* __restrict__ Vlg,
    float* __restrict__ O) {
  __shared__ unsigned short sKh[2][64 * 128], sKl[2][64 * 128];  // 2 x 32 KB
  int qb = blockIdx.y, bh = blockIdx.x;
  int b = bh >> 5, h = bh & 31;
  int tid = threadIdx.x;
  int lane = tid & 63, w = tid >> 6, quad = lane >> 4, c = lane & 15;
  int q0 = qb * 64 + w * 16;
  bfrag bqh[4], bql[4];
  {
    const unsigned short* qr = Qh + ((size_t)(b * 1024 + q0 + c)) * 4096 + h * 128 + quad * 8;
    const unsigned short* qrl = Ql + ((size_t)(b * 1024 + q0 + c)) * 4096 + h * 128 + quad * 8;
#pragma unroll
    for (int kd = 0; kd < 4; ++kd) {
      bqh[kd] = *(const bfrag*)(qr + kd * 32);
      bql[kd] = *(const bfrag*)(qrl + kd * 32);
    }
  }
  ffrag oacc[8] = {};
  float m_q = -INFINITY, l_q = 0.f;
  const float scale = 0.088388347648318447f;   // 1/sqrt(128)
  const unsigned short* Kb = Khg + ((size_t)b * 1024) * 4096 + h * 128;
  const unsigned short* Klb = Klg + ((size_t)b * 1024) * 4096 + h * 128;
  const unsigned short* Vb = Vhg + ((size_t)bh * 128) * 1024;
  const unsigned short* Vlb = Vlg + ((size_t)bh * 128) * 1024;
  int sA_ = ((quad & 1) << 5) + c;             // P-transpose src lanes
  int sB_ = sA_ + 16;
  int sr = lane >> 4, sch = lane & 15;         // staging: lane -> (subrow, chunk)

  auto STAGEK = [&](int buf, int kt) {
#pragma unroll
    for (int rr = 0; rr < 4; ++rr) {
      int row = rr * 16 + w * 4 + sr;
      size_t g = (size_t)(kt * 64 + row) * 4096 + ((sch ^ (row & 15)) * 8);
      __builtin_amdgcn_global_load_lds((gp_t)(Kb + g),
                                       (lp_t)&sKh[buf][(rr * 16 + w * 4) * 128],
                                       16, 0, 0);
      __builtin_amdgcn_global_load_lds((gp_t)(Klb + g),
                                       (lp_t)&sKl[buf][(rr * 16 + w * 4) * 128],
                                       16, 0, 0);
    }
  };

  STAGEK(0, 0);
  for (int kt = 0; kt <= qb; ++kt) {
    int cur = kt & 1;
    __syncthreads();                 // buf[cur] staged; prev reads of
                                     // buf[cur^1] complete
    if (kt < qb) STAGEK(cur ^ 1, kt + 1);
    // ---- S = K Q^T : D[row=key=quad*4+r, col=q=c] ----
    ffrag sf[4] = {};
    __builtin_amdgcn_s_setprio(1);
#pragma unroll
    for (int kd = 0; kd < 4; ++kd) {
      bfrag ah[4], al[4];
#pragma unroll
      for (int kb = 0; kb < 4; ++kb) {
        int off = ((kb * 16 + c) * 16 + ((kd * 4 + quad) ^ c)) * 8;
        ah[kb] = *(const bfrag*)&sKh[cur][off];
        al[kb] = *(const bfrag*)&sKl[cur][off];
      }
#pragma unroll
      for (int kb = 0; kb < 4; ++kb) {
        sf[kb] = MFMA16(ah[kb], bqh[kd], sf[kb]);
        sf[kb] = MFMA16(ah[kb], bql[kd], sf[kb]);
        sf[kb] = MFMA16(al[kb], bqh[kd], sf[kb]);
      }
    }
    __builtin_amdgcn_s_setprio(0);
    // ---- scale + causal mask + row max (per q = lane&15) ----
    float rmax = -INFINITY;
    bool diag = (kt == qb);
#pragma unroll
    for (int kb = 0; kb < 4; ++kb)
#pragma unroll
      for (int r = 0; r < 4; ++r) {
        float v = sf[kb][r] * scale;
        if (diag && (kb * 16 + quad * 4 + r) > (w * 16 + c)) v = -1e30f;
        sf[kb][r] = v;
        rmax = fmaxf(rmax, v);
      }
    rmax = fmaxf(rmax, __shfl_xor(rmax, 16, 64));
    rmax = fmaxf(rmax, __shfl_xor(rmax, 32, 64));
    // ---- defer-max (T13, THR=8): skip rescale while max growth small ----
    if (!__all(rmax <= m_q + 8.f)) {
      float mn = fmaxf(m_q, rmax);
      float alpha = __expf(m_q - mn);
      m_q = mn;
      l_q *= alpha;
      float al4[4];
#pragma unroll
      for (int r = 0; r < 4; ++r) al4[r] = __shfl(alpha, quad * 4 + r, 64);
#pragma unroll
      for (int db = 0; db < 8; ++db)
#pragma unroll
        for (int r = 0; r < 4; ++r) oacc[db][r] *= al4[r];
    }
    // ---- transpose S to A-layout (shuffles), exp (P <= e^8), split hi/lo ----
    bfrag ph[2], pl[2];
    float rsum = 0.f;
#pragma unroll
    for (int sblk = 0; sblk < 2; ++sblk)
#pragma unroll
      for (int j = 0; j < 8; ++j) {
        int srclane = (j < 4) ? sA_ : sB_;
        float v0 = __shfl(sf[sblk * 2 + 0][j & 3], srclane, 64);
        float v1 = __shfl(sf[sblk * 2 + 1][j & 3], srclane, 64);
        float v = (quad < 2) ? v0 : v1;
        float p = __expf(v - m_q);
        rsum += p;
        unsigned short hp = f2bf(p);
        ph[sblk][j] = (short)hp;
        pl[sblk][j] = (short)f2bf(p - bf2f(hp));
      }
    rsum += __shfl_xor(rsum, 16, 64);
    rsum += __shfl_xor(rsum, 32, 64);
    l_q += rsum;
    // ---- O += P Vt : D[row=q=quad*4+r, col=d=c] ----
    __builtin_amdgcn_s_setprio(1);
#pragma unroll
    for (int db = 0; db < 8; ++db) {
      const unsigned short* vrow = Vb + (size_t)(db * 16 + c) * 1024 + kt * 64;
      const unsigned short* vrowl = Vlb + (size_t)(db * 16 + c) * 1024 + kt * 64;
#pragma unroll
      for (int sblk = 0; sblk < 2; ++sblk) {
        bfrag vh_ = *(const bfrag*)(vrow + (sblk * 4 + quad) * 8);
        bfrag vl_ = *(const bfrag*)(vrowl + (sblk * 4 + quad) * 8);
        oacc[db] = MFMA16(ph[sblk], vh_, oacc[db]);
        oacc[db] = MFMA16(ph[sblk], vl_, oacc[db]);
        oacc[db] = MFMA16(pl[sblk], vh_, oacc[db]);
      }
    }
    __builtin_amdgcn_s_setprio(0);
  }
  float invl[4];
#pragma unroll
  for (int r = 0; r < 4; ++r) invl[r] = 1.f / __shfl(l_q, quad * 4 + r, 64);
#pragma unroll
  for (int db = 0; db < 8; ++db)
#pragma unroll
    for (int r = 0; r < 4; ++r)
      O[((size_t)(b * 1024 + q0 + quad * 4 + r)) * 4096 + h * 128 + db * 16 + c] =
          oacc[db][r] * invl[r];
}

// ---------------------------------------------------------------- launcher
extern "C" void kernel_launch(void* const* d_in, const int* in_sizes, int n_in,
                              void* d_out, int out_size, void* d_ws, size_t ws_size,
                              hipStream_t stream) {
  (void)in_sizes; (void)n_in; (void)out_size; (void)ws_size;
  const float* x = (const float*)d_in[0];
  const float* Wq = (const float*)d_in[1];
  const float* Wk = (const float*)d_in[2];
  const float* Wv = (const float*)d_in[3];
  const float* Wo = (const float*)d_in[4];
  float* out = (float*)d_out;
  char* ws = (char*)d_ws;
  const size_t MB = 1024ull * 1024ull;
  unsigned short* Xq = (unsigned short*)(ws);              // 16 MB (bf16 ints)
  float* Xs = (float*)(ws + 16 * MB);                      // 1 MB  (128 x 2048)
  unsigned short* Wqq = (unsigned short*)(ws + 24 * MB);   // 32 MB (bf16 ints)
  float* Ws = (float*)(ws + 56 * MB);                      // 2 MB  (128 x 4096)
  float* S1 = (float*)(ws + 64 * MB);                      // 32 MB fp32
  unsigned short* Qh = (unsigned short*)(ws + 96 * MB);    // 16 MB
  unsigned short* Ql = (unsigned short*)(ws + 112 * MB);
  unsigned short* Kh = (unsigned short*)(ws + 128 * MB);
  unsigned short* Kl = (unsigned short*)(ws + 144 * MB);
  unsigned short* Vh = (unsigned short*)(ws + 160 * MB);   // transposed [b,h,d,s]
  unsigned short* Vl = (unsigned short*)(ws + 176 * MB);

  dim3 gg(32, 16);
  quant_int_k<<<1024, 256, 0, stream>>>(x, Xq, Xs, 2048 * 128, 2048);
  quant_int_k<<<2048, 256, 0, stream>>>(Wq, Wqq, Ws, 4096 * 128, 4096);
  gemm_int_k<<<gg, 512, 0, stream>>>(Xq, Xs, Wqq, Ws, S1, nullptr, nullptr,
                                     2048, 4096, 4096, 0);
  rope_split_k<<<16384, 256, 0, stream>>>(S1, Qh, Ql);
  quant_int_k<<<2048, 256, 0, stream>>>(Wk, Wqq, Ws, 4096 * 128, 4096);
  gemm_int_k<<<gg, 512, 0, stream>>>(Xq, Xs, Wqq, Ws, S1, nullptr, nullptr,
                                     2048, 4096, 4096, 0);
  rope_split_k<<<16384, 256, 0, stream>>>(S1, Kh, Kl);
  quant_int_k<<<2048, 256, 0, stream>>>(Wv, Wqq, Ws, 4096 * 128, 4096);
  gemm_int_k<<<gg, 512, 0, stream>>>(Xq, Xs, Wqq, Ws, nullptr, Vh, Vl,
                                     2048, 4096, 4096, 1);
  attn_k<<<dim3(64, 16), 256, 0, stream>>>(Qh, Ql, Kh, Kl, Vh, Vl, S1);
  quant_int_k<<<1024, 256, 0, stream>>>(S1, Xq, Xs, 2048 * 128, 2048);
  quant_int_k<<<2048, 256, 0, stream>>>(Wo, Wqq, Ws, 4096 * 128, 4096);
  gemm_int_k<<<gg, 512, 0, stream>>>(Xq, Xs, Wqq, Ws, out, nullptr, nullptr,
                                     2048, 4096, 4096, 0);
}